// Round 1
// baseline (109.089 us; speedup 1.0000x reference)
//
#include <hip/hip_runtime.h>

#define B_  2
#define T_  2048
#define D_  512
#define H_  8
#define HD_ 64
#define WHALF_ 16
#define Mtot (B_*T_)
#define QKV_LD 1536

typedef __attribute__((ext_vector_type(8))) short short8;   // 8 bf16 in 4 VGPRs
typedef __attribute__((ext_vector_type(4))) short short4v;
typedef __attribute__((ext_vector_type(4))) float floatx4;  // MFMA accumulator

__device__ __forceinline__ unsigned short f2bf(float f) {
    unsigned u = __float_as_uint(f);
    u = (u + 0x7fffu + ((u >> 16) & 1u)) >> 16;   // RNE
    return (unsigned short)u;
}

__device__ __forceinline__ void glds16(const unsigned short* g, unsigned short* l) {
    // async global->LDS, 16 B/lane; LDS dest = wave-uniform base + lane*16
    __builtin_amdgcn_global_load_lds(
        (const __attribute__((address_space(1))) void*)g,
        (__attribute__((address_space(3))) void*)l, 16, 0, 0);
}

// ---------------------------------------------------------------------------
// Fused cast kernel (unchanged).
// ---------------------------------------------------------------------------
__global__ __launch_bounds__(256) void cast_all(
    const float* __restrict__ x,
    const float* __restrict__ Wq, const float* __restrict__ Wk,
    const float* __restrict__ Wv, const float* __restrict__ Wo,
    const float* __restrict__ bq, const float* __restrict__ bk,
    const float* __restrict__ bv,
    unsigned short* __restrict__ xb,
    unsigned short* __restrict__ wqkv, unsigned short* __restrict__ wob,
    float* __restrict__ bqkv)
{
    if (blockIdx.x < 2048) {
        int i = blockIdx.x * 256 + threadIdx.x;
        float4 f = ((const float4*)x)[i];
        ushort4 o;
        o.x = f2bf(f.x); o.y = f2bf(f.y); o.z = f2bf(f.z); o.w = f2bf(f.w);
        ((ushort4*)xb)[i] = o;
    } else if (blockIdx.x < 3072) {
        int gid = (blockIdx.x - 2048) * 256 + threadIdx.x;
        int m   = gid >> 16;
        int idx = gid & 0xFFFF;
        const float* src = (m == 0) ? Wq : (m == 1) ? Wk : (m == 2) ? Wv : Wo;
        float4 f = ((const float4*)src)[idx];
        ushort4 o;
        o.x = f2bf(f.x); o.y = f2bf(f.y); o.z = f2bf(f.z); o.w = f2bf(f.w);
        if (m < 3) ((ushort4*)wqkv)[(m << 16) + idx] = o;
        else       ((ushort4*)wob)[idx] = o;
    } else {
        for (int i = threadIdx.x; i < 384; i += 256) {
            const float* src = (i < 128) ? bq : (i < 256) ? bk : bv;
            ((float4*)bqkv)[i] = ((const float4*)src)[i & 127];
        }
    }
}

// ---------------------------------------------------------------------------
// m97-style 128x128-tile GEMM: C[M,CLD] = A[M,512] @ W[N,512]^T + bias.
// 4 waves in 2x2; each wave owns a 64x64 sub-tile (acc[4][4]); BK=64.
// Per K-step: 8 ds_read_b128 -> 16 MFMA (ratio 2.0 -- LDS-read cycles ==
// MFMA cycles, the balanced point from the m93/m97 ladder), vs the old
// 64x64 tile's 5 reads -> 4 MFMA (0.8, ~3.4x LDS-oversubscribed).
// Staging: XOR-swizzled glds16, 4 instrs/thread/operand/iter (128 rows).
// LDS 32 KB, ~160 VGPR -> 3 blocks/CU.
// OUTF32=0: bf16 out (GEMM1, CLD=1536).  OUTF32=1: f32 out (GEMM2, CLD=512).
// ---------------------------------------------------------------------------
template<int CLD, int OUTF32>
__global__ __launch_bounds__(256) void gemm128(
    const unsigned short* __restrict__ A, const unsigned short* __restrict__ W,
    const float* __restrict__ bias,
    unsigned short* __restrict__ Cb, float* __restrict__ Cf)
{
    __shared__ unsigned short As[128 * 64];
    __shared__ unsigned short Bs[128 * 64];

    const int t  = threadIdx.x;
    const int m0 = blockIdx.x * 128;
    const int n0 = blockIdx.y * 128;
    const int w  = t >> 6, l = t & 63;
    const int quad = l >> 4, lo = l & 15;

    const int lr  = l >> 3;                  // 0..7: row within 8-row chunk
    const int csw = ((l & 7) ^ lr) * 8;      // swizzled global col offset
    const unsigned short* Ag[4]; unsigned short* ldsA[4];
    const unsigned short* Bg[4]; unsigned short* ldsB[4];
    #pragma unroll
    for (int p = 0; p < 4; ++p) {
        Ag[p]   = A + (size_t)(m0 + 32 * w + 8 * p + lr) * 512 + csw;
        ldsA[p] = &As[(32 * w + 8 * p) * 64];
        Bg[p]   = W + (size_t)(n0 + 32 * w + 8 * p + lr) * 512 + csw;
        ldsB[p] = &Bs[(32 * w + 8 * p) * 64];
    }

    floatx4 acc[4][4];
    #pragma unroll
    for (int m = 0; m < 4; ++m)
        #pragma unroll
        for (int n = 0; n < 4; ++n) acc[m][n] = (floatx4)0.0f;

    const int wr = w >> 1, wc = w & 1;       // wave's 64x64 quadrant
    const int swlo = lo & 7;

    for (int k0 = 0; k0 < 512; k0 += 64) {
        #pragma unroll
        for (int p = 0; p < 4; ++p) { glds16(Ag[p] + k0, ldsA[p]); glds16(Bg[p] + k0, ldsB[p]); }
        __syncthreads();

        #pragma unroll
        for (int ks = 0; ks < 2; ++ks) {
            const int cg = ((ks * 4 + quad) ^ swlo) * 8;
            short8 a[4], b[4];
            #pragma unroll
            for (int m = 0; m < 4; ++m)
                a[m] = *(const short8*)(&As[(wr * 64 + m * 16 + lo) * 64 + cg]);
            #pragma unroll
            for (int n = 0; n < 4; ++n)
                b[n] = *(const short8*)(&Bs[(wc * 64 + n * 16 + lo) * 64 + cg]);
            #pragma unroll
            for (int m = 0; m < 4; ++m)
                #pragma unroll
                for (int n = 0; n < 4; ++n)
                    acc[m][n] = __builtin_amdgcn_mfma_f32_16x16x32_bf16(a[m], b[n], acc[m][n], 0, 0, 0);
        }
        __syncthreads();
    }

    #pragma unroll
    for (int n = 0; n < 4; ++n) {
        int col = n0 + wc * 64 + n * 16 + lo;
        float bv = bias[col];
        #pragma unroll
        for (int m = 0; m < 4; ++m) {
            #pragma unroll
            for (int r = 0; r < 4; ++r) {
                int row = m0 + wr * 64 + m * 16 + quad * 4 + r;
                if (OUTF32) Cf[(size_t)row * CLD + col] = acc[m][n][r] + bv;
                else        Cb[(size_t)row * CLD + col] = f2bf(acc[m][n][r] + bv);
            }
        }
    }
}

// ---------------------------------------------------------------------------
// MFMA local-window attention, band-restricted (unchanged this round).
// ---------------------------------------------------------------------------
#define QLD 72
#define VLD 76

__global__ __launch_bounds__(256) void attn_mfma(
    const unsigned short* __restrict__ qkv, unsigned short* __restrict__ att)
{
    __shared__ unsigned short Qs[64][QLD];
    __shared__ unsigned short Ks[96][QLD];
    __shared__ unsigned short Vs[96][VLD];
    __shared__ unsigned short Pws[4][16][QLD];   // cols relative to 32*ks0, 64 used

    const int q0 = blockIdx.x * 64;
    const int bh = blockIdx.y;
    const int b = bh >> 3, h = bh & 7;
    const int t = threadIdx.x;
    const int wq = t >> 6, l = t & 63;
    const int quad = l >> 4, lo = l & 15;

    const size_t baseQ = (size_t)(b * T_) * QKV_LD + h * HD_;

    for (int c = t; c < 512; c += 256) {          // Q: 64 rows
        int row = c >> 3, cg = c & 7;
        *(short8*)(&Qs[row][cg * 8]) =
            *(const short8*)(&qkv[baseQ + (size_t)(q0 + row) * QKV_LD + cg * 8]);
    }
    for (int c = t; c < 768; c += 256) {          // K: 96 rows
        int row = c >> 3, cg = c & 7;
        int g = q0 - WHALF_ + row;
        short8 kv = (short8)(short)0;
        if (g >= 0 && g < T_)
            kv = *(const short8*)(&qkv[baseQ + 512 + (size_t)g * QKV_LD + cg * 8]);
        *(short8*)(&Ks[row][cg * 8]) = kv;
    }
    for (int c = t; c < 768; c += 256) {          // V: 96 rows, row-major
        int row = c >> 3, cg = c & 7;
        int g = q0 - WHALF_ + row;
        short8 vv = (short8)(short)0;
        if (g >= 0 && g < T_)
            vv = *(const short8*)(&qkv[baseQ + 1024 + (size_t)g * QKV_LD + cg * 8]);
        // row stride 76 is not 8-aligned for b128; two 8 B writes (aligned)
        short4v lo4 = { vv[0], vv[1], vv[2], vv[3] };
        short4v hi4 = { vv[4], vv[5], vv[6], vv[7] };
        *(short4v*)(&Vs[row][cg * 8])     = lo4;
        *(short4v*)(&Vs[row][cg * 8 + 4]) = hi4;
    }
    __syncthreads();

    const int ks0 = wq >> 1;                      // first 32-key chunk
    const int kb  = ks0 * 2;                      // first 16-key tile

    // ---- S = Q K^T over 4 key tiles ----
    floatx4 S[4];
    #pragma unroll
    for (int tt = 0; tt < 4; ++tt) S[tt] = (floatx4)0.0f;
    short8 aq[2];
    #pragma unroll
    for (int ks = 0; ks < 2; ++ks)
        aq[ks] = *(const short8*)(&Qs[wq * 16 + lo][ks * 32 + quad * 8]);
    #pragma unroll
    for (int tt = 0; tt < 4; ++tt) {
        #pragma unroll
        for (int ks = 0; ks < 2; ++ks) {
            short8 bk8 = *(const short8*)(&Ks[(kb + tt) * 16 + lo][ks * 32 + quad * 8]);
            S[tt] = __builtin_amdgcn_mfma_f32_16x16x32_bf16(aq[ks], bk8, S[tt], 0, 0, 0);
        }
    }

    // ---- masked softmax; C-layout row=quad*4+r, col(key tile)=kb+tt ----
    float inv_r[4];
    #pragma unroll
    for (int r = 0; r < 4; ++r) {
        int qi = q0 + wq * 16 + quad * 4 + r;
        float mx = -1e30f;
        float sv[4]; bool vd[4];
        #pragma unroll
        for (int tt = 0; tt < 4; ++tt) {
            int j = q0 - WHALF_ + (kb + tt) * 16 + lo;
            bool ok = (j >= qi - WHALF_) && (j < qi + WHALF_) && (j >= 0) && (j < T_);
            float s = S[tt][r] * 0.125f;
            sv[tt] = s; vd[tt] = ok;
            mx = (ok && s > mx) ? s : mx;
        }
        #pragma unroll
        for (int mm = 1; mm < 16; mm <<= 1) mx = fmaxf(mx, __shfl_xor(mx, mm, 16));
        float den = 0.f;
        #pragma unroll
        for (int tt = 0; tt < 4; ++tt) {
            float e = vd[tt] ? __expf(sv[tt] - mx) : 0.f;
            Pws[wq][quad * 4 + r][tt * 16 + lo] = f2bf(e);
            den += e;
        }
        #pragma unroll
        for (int mm = 1; mm < 16; mm <<= 1) den += __shfl_xor(den, mm, 16);
        inv_r[r] = 1.0f / den;
    }
    // Pws is wave-private: in-wave lgkmcnt ordering suffices, no barrier.

    // ---- O = P V over 2 key chunks; B-frags gathered from row-major Vs ----
    floatx4 O[4];
    #pragma unroll
    for (int nt = 0; nt < 4; ++nt) O[nt] = (floatx4)0.0f;
    #pragma unroll
    for (int ksr = 0; ksr < 2; ++ksr) {
        short8 ap = *(const short8*)(&Pws[wq][lo][ksr * 32 + quad * 8]);
        const int krow = (ks0 + ksr) * 32 + quad * 8;
        #pragma unroll
        for (int nt = 0; nt < 4; ++nt) {
            short8 bv8;
            #pragma unroll
            for (int j = 0; j < 8; ++j)
                bv8[j] = (short)Vs[krow + j][nt * 16 + lo];
            O[nt] = __builtin_amdgcn_mfma_f32_16x16x32_bf16(ap, bv8, O[nt], 0, 0, 0);
        }
    }

    // ---- epilogue: scale by 1/den, bf16 out ----
    #pragma unroll
    for (int r = 0; r < 4; ++r) {
        int qi = q0 + wq * 16 + quad * 4 + r;
        size_t rowb = (size_t)(b * T_ + qi) * D_ + h * HD_;
        #pragma unroll
        for (int nt = 0; nt < 4; ++nt)
            att[rowb + nt * 16 + lo] = f2bf(O[nt][r] * inv_r[r]);
    }
}

// ---------------------------------------------------------------------------
extern "C" void kernel_launch(void* const* d_in, const int* in_sizes, int n_in,
                              void* d_out, int out_size, void* d_ws, size_t ws_size,
                              hipStream_t stream) {
    const float* x  = (const float*)d_in[0];
    const float* Wq = (const float*)d_in[1];
    const float* bq = (const float*)d_in[2];
    const float* Wk = (const float*)d_in[3];
    const float* bk = (const float*)d_in[4];
    const float* Wv = (const float*)d_in[5];
    const float* bv = (const float*)d_in[6];
    const float* Wo = (const float*)d_in[7];
    const float* bo = (const float*)d_in[8];
    float* out = (float*)d_out;

    char* ws = (char*)d_ws;
    unsigned short* xb   = (unsigned short*)(ws);                 //  4.00 MB
    unsigned short* wqkv = (unsigned short*)(ws +  4194304);      //  1.50 MB
    unsigned short* wob  = (unsigned short*)(ws +  5767168);      //  0.50 MB
    float*          bqkv = (float*)         (ws +  6291456);      //  6 KB
    unsigned short* qkvb = (unsigned short*)(ws +  6297600);      // 12.00 MB
    unsigned short* attb = (unsigned short*)(ws + 18880512);      //  4.00 MB

    cast_all<<<3073, 256, 0, stream>>>(x, Wq, Wk, Wv, Wo, bq, bk, bv,
                                       xb, wqkv, wob, bqkv);

    // fused QKV projection: 128x128 tiles, 32x12 = 384 blocks
    gemm128<QKV_LD, 0><<<dim3(Mtot / 128, QKV_LD / 128), 256, 0, stream>>>(
        xb, wqkv, bqkv, qkvb, nullptr);

    // local attention (band-restricted MFMA)
    attn_mfma<<<dim3(T_ / 64, B_ * H_), 256, 0, stream>>>(qkvb, attb);

    // output projection: 128x128 tiles, 32x4 = 128 blocks
    gemm128<D_, 1><<<dim3(Mtot / 128, D_ / 128), 256, 0, stream>>>(
        attb, wob, bo, nullptr, out);
}

// Round 2
// 101.484 us; speedup vs baseline: 1.0749x; 1.0749x over previous
//
#include <hip/hip_runtime.h>

#define B_  2
#define T_  2048
#define D_  512
#define H_  8
#define HD_ 64
#define WHALF_ 16
#define Mtot (B_*T_)

typedef __attribute__((ext_vector_type(8))) short short8;   // 8 bf16 in 4 VGPRs
typedef __attribute__((ext_vector_type(4))) short short4v;
typedef __attribute__((ext_vector_type(4))) float floatx4;  // MFMA accumulator

__device__ __forceinline__ unsigned short f2bf(float f) {
    unsigned u = __float_as_uint(f);
    u = (u + 0x7fffu + ((u >> 16) & 1u)) >> 16;   // RNE
    return (unsigned short)u;
}

__device__ __forceinline__ void glds16(const unsigned short* g, unsigned short* l) {
    // async global->LDS, 16 B/lane; LDS dest = wave-uniform base + lane*16
    __builtin_amdgcn_global_load_lds(
        (const __attribute__((address_space(1))) void*)g,
        (__attribute__((address_space(3))) void*)l, 16, 0, 0);
}

// ---------------------------------------------------------------------------
// Fused cast kernel. Also zeroes the 2 KB OOB-row scratch (zb).
// ---------------------------------------------------------------------------
__global__ __launch_bounds__(256) void cast_all(
    const float* __restrict__ x,
    const float* __restrict__ Wq, const float* __restrict__ Wk,
    const float* __restrict__ Wv, const float* __restrict__ Wo,
    const float* __restrict__ bq, const float* __restrict__ bk,
    const float* __restrict__ bv,
    unsigned short* __restrict__ xb,
    unsigned short* __restrict__ wqkv, unsigned short* __restrict__ wob,
    float* __restrict__ bqkv, unsigned short* __restrict__ zb)
{
    if (blockIdx.x < 2048) {
        int i = blockIdx.x * 256 + threadIdx.x;
        float4 f = ((const float4*)x)[i];
        ushort4 o;
        o.x = f2bf(f.x); o.y = f2bf(f.y); o.z = f2bf(f.z); o.w = f2bf(f.w);
        ((ushort4*)xb)[i] = o;
    } else if (blockIdx.x < 3072) {
        int gid = (blockIdx.x - 2048) * 256 + threadIdx.x;
        int m   = gid >> 16;
        int idx = gid & 0xFFFF;
        const float* src = (m == 0) ? Wq : (m == 1) ? Wk : (m == 2) ? Wv : Wo;
        float4 f = ((const float4*)src)[idx];
        ushort4 o;
        o.x = f2bf(f.x); o.y = f2bf(f.y); o.z = f2bf(f.z); o.w = f2bf(f.w);
        if (m < 3) ((ushort4*)wqkv)[(m << 16) + idx] = o;
        else       ((ushort4*)wob)[idx] = o;
    } else {
        for (int i = threadIdx.x; i < 384; i += 256) {
            const float* src = (i < 128) ? bq : (i < 256) ? bk : bv;
            ((float4*)bqkv)[i] = ((const float4*)src)[i & 127];
        }
        // zero 2 KB OOB scratch
        if (threadIdx.x < 128) {
            float4 z; z.x = 0.f; z.y = 0.f; z.z = 0.f; z.w = 0.f;
            ((float4*)zb)[threadIdx.x] = z;
        }
    }
}

// ---------------------------------------------------------------------------
// FUSED QKV-projection + local-window attention.
// One block per (64-query tile, head). In-block GEMM computes
//   Q[64x64] = x[q0..q0+64)   @ Wq[hcols]^T   (wave 0)
//   K[96x64] = x[q0-16..+80)  @ Wk[hcols]^T   (waves 1,3)
//   V[96x64] = x[q0-16..+80)  @ Wv[hcols]^T   (waves 2,3)
// straight into the attention LDS tiles (bias added, f2bf — bit-identical
// to the old gemm1->qkvb->attn path), then runs the proven band-restricted
// attention. Eliminates the 12 MB qkvb write + ~14 MB re-read + 1 launch.
// LDS: staging S 36 KB (overlaid with Pws) + Qs/Ks/Vs 37.6 KB = 72.75 KB
// -> 2 blocks/CU; grid 512 = exactly 2/CU.
// OOB x rows (only first/last q-tile) stage from a zeroed 2 KB scratch;
// those K/V rows are softmax-masked anyway.
// ---------------------------------------------------------------------------
#define QLD 72
#define VLD 76

__global__ __launch_bounds__(256) void qkv_attn(
    const unsigned short* __restrict__ xb,
    const unsigned short* __restrict__ wqkv,
    const float* __restrict__ bqkv,
    const unsigned short* __restrict__ zb,
    unsigned short* __restrict__ att)
{
    // S rows: [0..95] = x rows (q0-16 .. q0+79), [96..159]=Wq, [160..223]=Wk,
    // [224..287]=Wv (rows = output cols h*64..h*64+63). 64 bf16 per row (BK).
    __shared__ unsigned short S[288 * 64];        // 36 KB, reused as Pws later
    __shared__ unsigned short Qs[64][QLD];
    __shared__ unsigned short Ks[96][QLD];
    __shared__ unsigned short Vs[96][VLD];

    const int q0 = blockIdx.x * 64;
    const int bh = blockIdx.y;
    const int b = bh >> 3, h = bh & 7;
    const int t = threadIdx.x;
    const int w = t >> 6, l = t & 63;
    const int quad = l >> 4, lo = l & 15;
    const int lr  = l >> 3;
    const int csw = ((l & 7) ^ lr) * 8;      // swizzled source col offset

    // ---- staging pointers: 9 chunks/wave, 8 rows x 64 cols each ----
    const unsigned short* src[9];
    unsigned short* dst[9];
    #pragma unroll
    for (int i = 0; i < 9; ++i) {
        int c = w * 9 + i;
        dst[i] = &S[c * 512];
        if (c < 12) {                          // x rows 8c..8c+7 (g = q0-16+8c+lr)
            int g0 = q0 - 16 + 8 * c;          // chunks are fully in or fully out
            src[i] = (g0 >= 0 && g0 < T_)
                   ? (xb + (size_t)(b * T_ + g0 + lr) * 512 + csw)
                   : (zb + csw);               // zeros; +k0<=448 stays in 2 KB
        } else {                               // W region
            int wr0 = (c - 12) * 8;            // 0..191
            int m = wr0 >> 6;                  // 0=q,1=k,2=v
            int r = (wr0 & 63) + lr;           // output col within head
            src[i] = wqkv + (size_t)m * 262144 + (size_t)(h * 64 + r) * 512 + csw;
        }
    }

    floatx4 acc[4][4];
    #pragma unroll
    for (int m = 0; m < 4; ++m)
        #pragma unroll
        for (int n = 0; n < 4; ++n) acc[m][n] = (floatx4)0.0f;

    const int swlo = lo & 15 & 7;

    // ---- in-block GEMM: K=512, BK=64 ----
    for (int k0 = 0; k0 < 512; k0 += 64) {
        #pragma unroll
        for (int i = 0; i < 9; ++i) glds16(src[i] + k0, dst[i]);
        __syncthreads();

        #pragma unroll
        for (int ks = 0; ks < 2; ++ks) {
            const int cg = ((ks * 4 + quad) ^ swlo) * 8;
            if (w != 3) {
                // wave0: Q (x rows 16..79); wave1: K rows 0..63; wave2: V rows 0..63
                const int ab = (w == 0) ? 16 : 0;
                const int bb = 96 + (w << 6);
                short8 a[4], bf[4];
                #pragma unroll
                for (int m = 0; m < 4; ++m)
                    a[m] = *(const short8*)(&S[(ab + m * 16 + lo) * 64 + cg]);
                #pragma unroll
                for (int n = 0; n < 4; ++n)
                    bf[n] = *(const short8*)(&S[(bb + n * 16 + lo) * 64 + cg]);
                #pragma unroll
                for (int m = 0; m < 4; ++m)
                    #pragma unroll
                    for (int n = 0; n < 4; ++n)
                        acc[m][n] = __builtin_amdgcn_mfma_f32_16x16x32_bf16(a[m], bf[n], acc[m][n], 0, 0, 0);
            } else {
                // wave3: K rows 64..95 (acc[0..1]) + V rows 64..95 (acc[2..3])
                short8 a2[2], bk4[4], bv4[4];
                #pragma unroll
                for (int j = 0; j < 2; ++j)
                    a2[j] = *(const short8*)(&S[(64 + j * 16 + lo) * 64 + cg]);
                #pragma unroll
                for (int n = 0; n < 4; ++n) {
                    bk4[n] = *(const short8*)(&S[(160 + n * 16 + lo) * 64 + cg]);
                    bv4[n] = *(const short8*)(&S[(224 + n * 16 + lo) * 64 + cg]);
                }
                #pragma unroll
                for (int n = 0; n < 4; ++n) {
                    acc[0][n] = __builtin_amdgcn_mfma_f32_16x16x32_bf16(a2[0], bk4[n], acc[0][n], 0, 0, 0);
                    acc[1][n] = __builtin_amdgcn_mfma_f32_16x16x32_bf16(a2[1], bk4[n], acc[1][n], 0, 0, 0);
                    acc[2][n] = __builtin_amdgcn_mfma_f32_16x16x32_bf16(a2[0], bv4[n], acc[2][n], 0, 0, 0);
                    acc[3][n] = __builtin_amdgcn_mfma_f32_16x16x32_bf16(a2[1], bv4[n], acc[3][n], 0, 0, 0);
                }
            }
        }
        __syncthreads();
    }

    // ---- epilogue: Q/K/V -> attn LDS tiles, bias + f2bf ----
    if (w == 0) {
        #pragma unroll
        for (int n = 0; n < 4; ++n) {
            float bb = bqkv[h * 64 + n * 16 + lo];
            #pragma unroll
            for (int m = 0; m < 4; ++m)
                #pragma unroll
                for (int r = 0; r < 4; ++r)
                    Qs[m * 16 + quad * 4 + r][n * 16 + lo] = f2bf(acc[m][n][r] + bb);
        }
    } else if (w == 1) {
        #pragma unroll
        for (int n = 0; n < 4; ++n) {
            float bb = bqkv[512 + h * 64 + n * 16 + lo];
            #pragma unroll
            for (int m = 0; m < 4; ++m)
                #pragma unroll
                for (int r = 0; r < 4; ++r)
                    Ks[m * 16 + quad * 4 + r][n * 16 + lo] = f2bf(acc[m][n][r] + bb);
        }
    } else if (w == 2) {
        #pragma unroll
        for (int n = 0; n < 4; ++n) {
            float bb = bqkv[1024 + h * 64 + n * 16 + lo];
            #pragma unroll
            for (int m = 0; m < 4; ++m)
                #pragma unroll
                for (int r = 0; r < 4; ++r)
                    Vs[m * 16 + quad * 4 + r][n * 16 + lo] = f2bf(acc[m][n][r] + bb);
        }
    } else {
        #pragma unroll
        for (int n = 0; n < 4; ++n) {
            float bbk = bqkv[512  + h * 64 + n * 16 + lo];
            float bbv = bqkv[1024 + h * 64 + n * 16 + lo];
            #pragma unroll
            for (int j = 0; j < 2; ++j)
                #pragma unroll
                for (int r = 0; r < 4; ++r) {
                    Ks[64 + j * 16 + quad * 4 + r][n * 16 + lo] = f2bf(acc[j][n][r] + bbk);
                    Vs[64 + j * 16 + quad * 4 + r][n * 16 + lo] = f2bf(acc[2 + j][n][r] + bbv);
                }
        }
    }
    __syncthreads();

    // ---- attention phase (proven band-restricted structure) ----
    unsigned short (*Pws)[16][QLD] = (unsigned short (*)[16][QLD])S;  // overlay

    const int wq  = w;
    const int ks0 = wq >> 1;                      // first 32-key chunk
    const int kb  = ks0 * 2;                      // first 16-key tile

    // S = Q K^T over 4 key tiles
    floatx4 Sf[4];
    #pragma unroll
    for (int tt = 0; tt < 4; ++tt) Sf[tt] = (floatx4)0.0f;
    short8 aq[2];
    #pragma unroll
    for (int ks = 0; ks < 2; ++ks)
        aq[ks] = *(const short8*)(&Qs[wq * 16 + lo][ks * 32 + quad * 8]);
    #pragma unroll
    for (int tt = 0; tt < 4; ++tt) {
        #pragma unroll
        for (int ks = 0; ks < 2; ++ks) {
            short8 bk8 = *(const short8*)(&Ks[(kb + tt) * 16 + lo][ks * 32 + quad * 8]);
            Sf[tt] = __builtin_amdgcn_mfma_f32_16x16x32_bf16(aq[ks], bk8, Sf[tt], 0, 0, 0);
        }
    }

    // masked softmax
    float inv_r[4];
    #pragma unroll
    for (int r = 0; r < 4; ++r) {
        int qi = q0 + wq * 16 + quad * 4 + r;
        float mx = -1e30f;
        float sv[4]; bool vd[4];
        #pragma unroll
        for (int tt = 0; tt < 4; ++tt) {
            int j = q0 - WHALF_ + (kb + tt) * 16 + lo;
            bool ok = (j >= qi - WHALF_) && (j < qi + WHALF_) && (j >= 0) && (j < T_);
            float s = Sf[tt][r] * 0.125f;
            sv[tt] = s; vd[tt] = ok;
            mx = (ok && s > mx) ? s : mx;
        }
        #pragma unroll
        for (int mm = 1; mm < 16; mm <<= 1) mx = fmaxf(mx, __shfl_xor(mx, mm, 16));
        float den = 0.f;
        #pragma unroll
        for (int tt = 0; tt < 4; ++tt) {
            float e = vd[tt] ? __expf(sv[tt] - mx) : 0.f;
            Pws[wq][quad * 4 + r][tt * 16 + lo] = f2bf(e);
            den += e;
        }
        #pragma unroll
        for (int mm = 1; mm < 16; mm <<= 1) den += __shfl_xor(den, mm, 16);
        inv_r[r] = 1.0f / den;
    }
    // Pws is wave-private: in-wave lgkmcnt ordering suffices, no barrier.

    // O = P V over 2 key chunks; B-frags gathered from row-major Vs
    floatx4 O[4];
    #pragma unroll
    for (int nt = 0; nt < 4; ++nt) O[nt] = (floatx4)0.0f;
    #pragma unroll
    for (int ksr = 0; ksr < 2; ++ksr) {
        short8 ap = *(const short8*)(&Pws[wq][lo][ksr * 32 + quad * 8]);
        const int krow = (ks0 + ksr) * 32 + quad * 8;
        #pragma unroll
        for (int nt = 0; nt < 4; ++nt) {
            short8 bv8;
            #pragma unroll
            for (int j = 0; j < 8; ++j)
                bv8[j] = (short)Vs[krow + j][nt * 16 + lo];
            O[nt] = __builtin_amdgcn_mfma_f32_16x16x32_bf16(ap, bv8, O[nt], 0, 0, 0);
        }
    }

    // epilogue: scale by 1/den, bf16 out
    #pragma unroll
    for (int r = 0; r < 4; ++r) {
        int qi = q0 + wq * 16 + quad * 4 + r;
        size_t rowb = (size_t)(b * T_ + qi) * D_ + h * HD_;
        #pragma unroll
        for (int nt = 0; nt < 4; ++nt)
            att[rowb + nt * 16 + lo] = f2bf(O[nt][r] * inv_r[r]);
    }
}

// ---------------------------------------------------------------------------
// GEMM2: out[4096,512](f32) = attb(bf16) @ wob^T + bo.
// 64x64 tile, 512 blocks = 2/CU; 2x2 wave split (32x32/wave): per K-step
// 4 ds_read_b128 for 4 MFMA (vs 5:4 for the old 1x4 split).
// ---------------------------------------------------------------------------
__global__ __launch_bounds__(256) void gemm_out(
    const unsigned short* __restrict__ attb, const unsigned short* __restrict__ wob,
    const float* __restrict__ bo, float* __restrict__ out)
{
    __shared__ unsigned short As[64 * 64];
    __shared__ unsigned short Bs[64 * 64];

    const int t  = threadIdx.x;
    const int m0 = blockIdx.x * 64;
    const int n0 = blockIdx.y * 64;
    const int w  = t >> 6, l = t & 63;
    const int quad = l >> 4, lo = l & 15;

    const int lr = l >> 3;
    const int csw = ((l & 7) ^ lr) * 8;
    const unsigned short* Ag[2]; unsigned short* ldsA[2];
    const unsigned short* Bg[2]; unsigned short* ldsB[2];
    #pragma unroll
    for (int p = 0; p < 2; ++p) {
        Ag[p] = attb + (size_t)(m0 + 16 * w + 8 * p + lr) * 512 + csw;
        ldsA[p] = &As[(16 * w + 8 * p) * 64];
        Bg[p] = wob + (size_t)(n0 + 16 * w + 8 * p + lr) * 512 + csw;
        ldsB[p] = &Bs[(16 * w + 8 * p) * 64];
    }

    floatx4 acc[2][2];
    #pragma unroll
    for (int m = 0; m < 2; ++m)
        #pragma unroll
        for (int n = 0; n < 2; ++n) acc[m][n] = (floatx4)0.0f;

    const int wr = w >> 1, wc = w & 1;
    const int swlo = lo & 7;

    for (int k0 = 0; k0 < 512; k0 += 64) {
        #pragma unroll
        for (int p = 0; p < 2; ++p) { glds16(Ag[p] + k0, ldsA[p]); glds16(Bg[p] + k0, ldsB[p]); }
        __syncthreads();

        #pragma unroll
        for (int ks = 0; ks < 2; ++ks) {
            const int cg = ((ks * 4 + quad) ^ swlo) * 8;
            short8 a[2], bf[2];
            #pragma unroll
            for (int m = 0; m < 2; ++m)
                a[m] = *(const short8*)(&As[(wr * 32 + m * 16 + lo) * 64 + cg]);
            #pragma unroll
            for (int n = 0; n < 2; ++n)
                bf[n] = *(const short8*)(&Bs[(wc * 32 + n * 16 + lo) * 64 + cg]);
            #pragma unroll
            for (int m = 0; m < 2; ++m)
                #pragma unroll
                for (int n = 0; n < 2; ++n)
                    acc[m][n] = __builtin_amdgcn_mfma_f32_16x16x32_bf16(a[m], bf[n], acc[m][n], 0, 0, 0);
        }
        __syncthreads();
    }

    #pragma unroll
    for (int n = 0; n < 2; ++n) {
        int col = n0 + wc * 32 + n * 16 + lo;
        float bv = bo[col];
        #pragma unroll
        for (int m = 0; m < 2; ++m) {
            #pragma unroll
            for (int r = 0; r < 4; ++r) {
                int row = m0 + wr * 32 + m * 16 + quad * 4 + r;
                out[(size_t)row * 512 + col] = acc[m][n][r] + bv;
            }
        }
    }
}

// ---------------------------------------------------------------------------
extern "C" void kernel_launch(void* const* d_in, const int* in_sizes, int n_in,
                              void* d_out, int out_size, void* d_ws, size_t ws_size,
                              hipStream_t stream) {
    const float* x  = (const float*)d_in[0];
    const float* Wq = (const float*)d_in[1];
    const float* bq = (const float*)d_in[2];
    const float* Wk = (const float*)d_in[3];
    const float* bk = (const float*)d_in[4];
    const float* Wv = (const float*)d_in[5];
    const float* bv = (const float*)d_in[6];
    const float* Wo = (const float*)d_in[7];
    const float* bo = (const float*)d_in[8];
    float* out = (float*)d_out;

    char* ws = (char*)d_ws;
    unsigned short* xb   = (unsigned short*)(ws);                 //  4.00 MB
    unsigned short* wqkv = (unsigned short*)(ws +  4194304);      //  1.50 MB
    unsigned short* wob  = (unsigned short*)(ws +  5767168);      //  0.50 MB
    float*          bqkv = (float*)         (ws +  6291456);      //  6 KB
    unsigned short* zb   = (unsigned short*)(ws +  6297600);      //  2 KB zeros
    unsigned short* attb = (unsigned short*)(ws +  6299648);      //  4.00 MB

    cast_all<<<3073, 256, 0, stream>>>(x, Wq, Wk, Wv, Wo, bq, bk, bv,
                                       xb, wqkv, wob, bqkv, zb);

    // fused QKV projection + local attention: 512 blocks = 2/CU
    qkv_attn<<<dim3(T_ / 64, B_ * H_), 256, 0, stream>>>(
        xb, wqkv, bqkv, zb, attb);

    // output projection: 64x64 tiles, 512 blocks = 2/CU
    gemm_out<<<dim3(Mtot / 64, D_ / 64), 256, 0, stream>>>(attb, wob, bo, out);
}